// Round 2
// baseline (189.831 us; speedup 1.0000x reference)
//
#include <hip/hip_runtime.h>
#include <stdint.h>

#define B_    32768
#define C_    64
#define D_    8
#define K15_  15
#define K16_  16
#define OUT_  512

typedef _Float16 half4v __attribute__((ext_vector_type(4)));
typedef _Float16 half8  __attribute__((ext_vector_type(8)));

// workspace layout (bytes)
#define AMAP_OFF  0
#define AMAP_SZ   32768                  // uint8 argmax per 15-bit code
#define S64_OFF   32768                  // fp64 S, k-major: S64[c][k][d]
#define S64_SZ    (64 * 15 * 8 * 8)      // 61440
#define T64_OFF   (S64_OFF + S64_SZ)     // 94208
#define T64_SZ    (64 * 15 * 8)          // 7680
#define IDX_OFF   (T64_OFF + T64_SZ)     // 101888
#define IDX_SZ    (B_ * C_)              // 2 MB. pairs mode: idxo unused ->
                                         // region reused for S32/T32 (fp32,
                                         // k-major) so WS_NEED is unchanged.
#define S32_SZ    (64 * 15 * 8 * 4)      // 30720
#define PCT_OFF   (IDX_OFF + IDX_SZ)     // 2199040
#define PCT_SZ    (B_ * 32)              // 1 MB: pcT[p][rg][tr][i]
#define PTAB_OFF  (PCT_OFF + PCT_SZ)     // 3247616 (16B aligned)
#define PTAB_SZ   (32 * 32 * 256 * 16 * 2) // 8388608: P5[p][jc][q][16] fp16
#define WS_NEED   ((size_t)PTAB_OFF + PTAB_SZ)

// ---------------------------------------------------------------------------
// k_setup (fused): 2048 blocks write P5 (j-first layout, fully coalesced
// 16B stores); blocks 0..127 also compute amap; block 128 builds S64/T64
// (+ S32/T32 fp32 copies when do_pairs).
// P5 half-index: ((p*32 + jc)*256 + q)*16 + e   (q = (t0<<4)|t1)
// ---------------------------------------------------------------------------
__global__ __launch_bounds__(256) void k_setup(const float* __restrict__ LUT,
                                               const float* __restrict__ H,
                                               const float* __restrict__ S,
                                               const float* __restrict__ T,
                                               _Float16* __restrict__ P5,
                                               uint8_t* __restrict__ amap,
                                               double* __restrict__ S64,
                                               double* __restrict__ T64,
                                               float* __restrict__ S32,
                                               float* __restrict__ T32,
                                               int do_pairs) {
    int gid = blockIdx.x * 256 + threadIdx.x;

    if (do_pairs) {
        // gid bits: [p:5][jc:5][q:8][e8:1] -> write offset = gid*8 halfs
        int e8 = gid & 1;
        int q = (gid >> 1) & 255;
        int jc = (gid >> 9) & 31;
        int p = gid >> 14;
        int t0 = q >> 4;
        int t1 = q & 15;
        int j0 = jc * 16 + e8 * 8;
        const float* u = LUT + (size_t)((2 * p) * 16 + t0) * 512 + j0;
        const float* v = LUT + (size_t)((2 * p + 1) * 16 + t1) * 512 + j0;
        float4 u0 = ((const float4*)u)[0];
        float4 u1 = ((const float4*)u)[1];
        float4 v0 = ((const float4*)v)[0];
        float4 v1 = ((const float4*)v)[1];
        half8 w;
        w[0] = (_Float16)(u0.x + v0.x);
        w[1] = (_Float16)(u0.y + v0.y);
        w[2] = (_Float16)(u0.z + v0.z);
        w[3] = (_Float16)(u0.w + v0.w);
        w[4] = (_Float16)(u1.x + v1.x);
        w[5] = (_Float16)(u1.y + v1.y);
        w[6] = (_Float16)(u1.z + v1.z);
        w[7] = (_Float16)(u1.w + v1.w);
        *(half8*)(P5 + (size_t)gid * 8) = w;
    }

    if (blockIdx.x < 128) {
        int code = gid;
        double h[K16_];
#pragma unroll
        for (int j = 0; j < K16_; ++j) h[j] = 0.0;
#pragma unroll
        for (int k = 0; k < K15_; ++k) {
            double s = ((code >> k) & 1) ? 1.0 : -1.0;
#pragma unroll
            for (int j = 0; j < K16_; ++j) h[j] += s * (double)H[k * K16_ + j];
        }
        double best = h[0];
        int bi = 0;
#pragma unroll
        for (int j = 1; j < K16_; ++j) {
            if (h[j] > best) { best = h[j]; bi = j; }
        }
        amap[code] = (uint8_t)bi;
    } else if (blockIdx.x == 128) {
        for (int i = threadIdx.x; i < 64 * 15 * 8; i += 256) {
            int c = i / 120;
            int r = i - c * 120;  // r = k*8 + d
            int k = r >> 3;
            int d = r & 7;
            float sv = S[c * 120 + d * 15 + k];
            S64[i] = (double)sv;
            if (do_pairs) S32[i] = sv;
        }
        for (int i = threadIdx.x; i < 64 * 15; i += 256) {
            T64[i] = (double)T[i];
            if (do_pairs) T32[i] = T[i];
        }
    }
}

// ---------------------------------------------------------------------------
// k_codes2: block = 256 thr (4 waves), 64 batches per block.
// Stage x into LDS transposed, wave<->channel, lane<->batch: S/T wave-uniform
// scalar loads. FAST=1: fp32 dot products (2x VALU rate of fp64) with fp64
// rescue when min_k |p_k| < EPS (fp32 err bound ~1e-5, EPS=1e-4 -> codes
// bit-identical to the all-fp64 version; rescue rate ~5e-4/channel). FAST=1
// also skips the idxo store (unused in pairs mode).
// Writes transposed pair codes pcT[p][rg=row>>10][tr=row&127][i=(row&1023)>>7].
// ---------------------------------------------------------------------------
#define XSTRIDE 585   // odd -> conflict-free
template <int FAST>
__global__ __launch_bounds__(256) void k_codes2(const float* __restrict__ x,
                                                const double* __restrict__ S64,
                                                const double* __restrict__ T64,
                                                const float* __restrict__ S32,
                                                const float* __restrict__ T32,
                                                const uint8_t* __restrict__ amap,
                                                uint8_t* __restrict__ idxo,
                                                uint8_t* __restrict__ pcT) {
    __shared__ float xls[32 * XSTRIDE];
    __shared__ uint8_t idsh[64 * 68];

    int b0 = blockIdx.x * 64;
    int lane = threadIdx.x & 63;
    int wv = __builtin_amdgcn_readfirstlane(threadIdx.x >> 6);

    for (int half = 0; half < 2; ++half) {
        __syncthreads();
#pragma unroll
        for (int t = 0; t < 16; ++t) {
            int e = t * 256 + threadIdx.x;
            int b = e >> 6;
            int j4 = e & 63;
            float4 v = ((const float4*)(x + (size_t)(b0 + b) * 512 +
                                        half * 256))[j4];
            int cl = j4 >> 1;
            int d0 = (j4 & 1) * 4;
            float* dst = &xls[cl * XSTRIDE + b * 9 + d0];
            dst[0] = v.x; dst[1] = v.y; dst[2] = v.z; dst[3] = v.w;
        }
        __syncthreads();
        for (int i = 0; i < 8; ++i) {
            int cl = wv + i * 4;                 // wave-uniform
            int c = half * 32 + cl;
            unsigned code = 0;
            if (FAST) {
                const float* Sc = S32 + c * 120;  // k-major: Sc[k*8+d]
                const float* Tc = T32 + c * 15;
                float xf[8];
#pragma unroll
                for (int d = 0; d < 8; ++d)
                    xf[d] = xls[cl * XSTRIDE + lane * 9 + d];
                float pmin = 3.0e38f;
#pragma unroll
                for (int k = 0; k < K15_; ++k) {
                    float p = -Tc[k];
#pragma unroll
                    for (int d = 0; d < 8; ++d)
                        p = fmaf(xf[d], Sc[k * 8 + d], p);
                    code |= (p > 0.f) ? (1u << k) : 0u;
                    pmin = fminf(pmin, fabsf(p));
                }
                if (pmin < 1e-4f) {  // rare: redo channel in fp64
                    const double* Sd = S64 + c * 120;
                    const double* Td = T64 + c * 15;
                    code = 0;
#pragma unroll
                    for (int k = 0; k < K15_; ++k) {
                        double p = -Td[k];
#pragma unroll
                        for (int d = 0; d < 8; ++d)
                            p = fma((double)xf[d], Sd[k * 8 + d], p);
                        code |= (p > 0.0) ? (1u << k) : 0u;
                    }
                }
            } else {
                const double* Sc = S64 + c * 120;  // k-major: Sc[k*8+d]
                const double* Tc = T64 + c * 15;
                double xd[8];
#pragma unroll
                for (int d = 0; d < 8; ++d)
                    xd[d] = (double)xls[cl * XSTRIDE + lane * 9 + d];
#pragma unroll
                for (int k = 0; k < K15_; ++k) {
                    double p = -Tc[k];
#pragma unroll
                    for (int d = 0; d < 8; ++d)
                        p = fma(xd[d], Sc[k * 8 + d], p);
                    code |= (p > 0.0) ? (1u << k) : 0u;
                }
            }
            idsh[lane * 68 + c] = amap[code];
        }
    }
    __syncthreads();

    int bb = threadIdx.x >> 2;
    int q = threadIdx.x & 3;
    if (!FAST) {
        uint32_t w0 = *(const uint32_t*)&idsh[bb * 68 + q * 16 + 0];
        uint32_t w1 = *(const uint32_t*)&idsh[bb * 68 + q * 16 + 4];
        uint32_t w2 = *(const uint32_t*)&idsh[bb * 68 + q * 16 + 8];
        uint32_t w3 = *(const uint32_t*)&idsh[bb * 68 + q * 16 + 12];
        uint32_t* o = (uint32_t*)(idxo + (size_t)(b0 + bb) * 64 + q * 16);
        o[0] = w0; o[1] = w1; o[2] = w2; o[3] = w3;
    }
    {
        int row = b0 + bb;
        int rg = row >> 10;
        int tr = row & 127;
        int i_ = (row & 1023) >> 7;
        uint8_t* base = pcT + rg * 1024 + tr * 8 + i_;
#pragma unroll
        for (int pi = 0; pi < 8; ++pi) {
            int p = q * 8 + pi;
            uint8_t byte = (uint8_t)((idsh[bb * 68 + 2 * p] << 4) |
                                     idsh[bb * 68 + 2 * p + 1]);
            base[p * 32768] = byte;
        }
    }
}

// ---------------------------------------------------------------------------
// k_main7: streaming-staged gather, v3.
// Changes vs k_main6:
//   * grid 1024 -> 2048 (512 rows/block): 6 resident blocks/CU (LDS-capped at
//     147 KB) instead of 4 -> more TLP to fill barrier-skew/latency bubbles.
//     launch_bounds(256,6) (VGPR cap 85; we use ~60).
//   * accumulate via fmaf((float)v, 1.0f, acc) -> v_fma_mix_f32 (1 instr/elem
//     instead of cvt+add), halving accumulation VALU. Exact (x*1.0+acc).
// Retained: 48B slab rows (single ds_read_b128/gather, uniform quad walk),
// double-buffered slab, prefetch-before-barrier, jc=blk&31 XCD pinning.
// ---------------------------------------------------------------------------
__global__ __launch_bounds__(256, 6) void k_main7(const uint8_t* __restrict__ pcT,
                                                  const _Float16* __restrict__ P5,
                                                  float* __restrict__ out) {
    __shared__ alignas(16) _Float16 slab[2][256 * 24];  // 48 B per code row

    int rg5 = blockIdx.x >> 5;   // 0..63, owns rows rg5*512 + i*128 + tr
    int jc = blockIdx.x & 31;
    int t = threadIdx.x;
    int tc = t & 1;        // which 8-half piece of the 16-half chunk
    int tr = t >> 1;       // 0..127

    // pcT[p][rg][tr][i_]: for row = rg5*512 + i*128 + tr:
    //   rg = rg5>>1, i_ = (rg5&1)*4 + i  -> 4 consecutive bytes
    const uint8_t* cbase = pcT + (rg5 >> 1) * 1024 + tr * 8 + (rg5 & 1) * 4;

    float acc[4][8];
#pragma unroll
    for (int i = 0; i < 4; ++i)
#pragma unroll
        for (int e = 0; e < 8; ++e) acc[i][e] = 0.f;

    // prefetch p=0
    const _Float16* src0 = P5 + ((size_t)jc * 256 + t) * 16;
    half8 g0 = ((const half8*)src0)[0];
    half8 g1 = ((const half8*)src0)[1];
    uint32_t cw = *(const uint32_t*)cbase;

    for (int p = 0; p < 32; ++p) {
        // stage slab for p into buffer p&1 (aligned b128 writes, no conflict)
        _Float16* wb = &slab[p & 1][0];
        *(half8*)(wb + t * 24) = g0;
        *(half8*)(wb + t * 24 + 8) = g1;

        uint32_t cw_cur = cw;
        if (p < 31) {  // issue prefetch of p+1 BEFORE the barrier
            const _Float16* srcn =
                P5 + ((size_t)((p + 1) * 32 + jc) * 256 + t) * 16;
            g0 = ((const half8*)srcn)[0];
            g1 = ((const half8*)srcn)[1];
            cw = *(const uint32_t*)(cbase + (size_t)(p + 1) * 32768);
        }

        __syncthreads();  // slab p ready; also fences gather(p-1) vs write(p+1)

        const _Float16* rb = &slab[p & 1][0] + tc * 8;
#pragma unroll
        for (int i = 0; i < 4; ++i) {
            int ci = (int)((cw_cur >> (8 * i)) & 0xFF);
            half8 v = *(const half8*)(rb + ci * 24);  // one ds_read_b128
#pragma unroll
            for (int e = 0; e < 8; ++e)
                acc[i][e] = fmaf((float)v[e], 1.0f, acc[i][e]);
        }
    }

#pragma unroll
    for (int i = 0; i < 4; ++i) {
        int row = rg5 * 512 + i * 128 + tr;
        float* o = out + (size_t)row * 512 + jc * 16 + tc * 8;
        float4 w0;
        w0.x = acc[i][0]; w0.y = acc[i][1]; w0.z = acc[i][2]; w0.w = acc[i][3];
        float4 w1;
        w1.x = acc[i][4]; w1.y = acc[i][5]; w1.z = acc[i][6]; w1.w = acc[i][7];
        ((float4*)o)[0] = w0;
        ((float4*)o)[1] = w1;
    }
}

// Fallback (small ws): direct 64-channel gather from fp32 LUT.
__global__ __launch_bounds__(256) void k_main_direct(const uint8_t* __restrict__ idx,
                                                     const float* __restrict__ LUT,
                                                     float* __restrict__ out) {
    int j4 = threadIdx.x & 127;
    int sub = threadIdx.x >> 7;
    int b0 = blockIdx.x * 16 + sub * 8;
    const float4* L4 = (const float4*)LUT;
    for (int r = 0; r < 8; ++r) {
        int b = b0 + r;
        const uint32_t* iw = (const uint32_t*)(idx + (size_t)b * 64);
        float4 acc;
        acc.x = 0.f; acc.y = 0.f; acc.z = 0.f; acc.w = 0.f;
#pragma unroll
        for (int i = 0; i < 16; ++i) {
            uint32_t w = __builtin_amdgcn_readfirstlane(iw[i]);
#pragma unroll
            for (int t = 0; t < 4; ++t) {
                int c = i * 4 + t;
                uint32_t codev = (w >> (8 * t)) & 0xFu;
                float4 v = L4[(size_t)(c * 16 + codev) * 128 + j4];
                acc.x += v.x; acc.y += v.y; acc.z += v.z; acc.w += v.w;
            }
        }
        ((float4*)(out + (size_t)b * 512))[j4] = acc;
    }
}

extern "C" void kernel_launch(void* const* d_in, const int* in_sizes, int n_in,
                              void* d_out, int out_size, void* d_ws, size_t ws_size,
                              hipStream_t stream) {
    const float* x   = (const float*)d_in[0];
    const float* S   = (const float*)d_in[1];
    const float* H   = (const float*)d_in[2];
    const float* T   = (const float*)d_in[3];
    const float* LUT = (const float*)d_in[4];
    float* out = (float*)d_out;

    uint8_t* ws = (uint8_t*)d_ws;
    uint8_t* amap = ws + AMAP_OFF;
    double* S64   = (double*)(ws + S64_OFF);
    double* T64   = (double*)(ws + T64_OFF);
    uint8_t* idxb = ws + IDX_OFF;                  // fallback mode only
    float* S32    = (float*)(ws + IDX_OFF);        // pairs mode only
    float* T32    = (float*)(ws + IDX_OFF + S32_SZ);
    uint8_t* pcTb = ws + PCT_OFF;
    _Float16* P5  = (_Float16*)(ws + PTAB_OFF);

    bool use_pairs = ws_size >= WS_NEED;

    hipLaunchKernelGGL(k_setup, dim3(use_pairs ? 2048 : 129), dim3(256), 0,
                       stream, LUT, H, S, T, P5, amap, S64, T64, S32, T32,
                       use_pairs ? 1 : 0);
    if (use_pairs) {
        hipLaunchKernelGGL((k_codes2<1>), dim3(B_ / 64), dim3(256), 0, stream,
                           x, S64, T64, S32, T32, amap, idxb, pcTb);
        hipLaunchKernelGGL(k_main7, dim3(2048), dim3(256), 0, stream,
                           pcTb, P5, out);
    } else {
        hipLaunchKernelGGL((k_codes2<0>), dim3(B_ / 64), dim3(256), 0, stream,
                           x, S64, T64, S32, T32, amap, idxb, pcTb);
        hipLaunchKernelGGL(k_main_direct, dim3(B_ / 16), dim3(256), 0, stream,
                           idxb, LUT, out);
    }
}

// Round 3
// 187.929 us; speedup vs baseline: 1.0101x; 1.0101x over previous
//
#include <hip/hip_runtime.h>
#include <stdint.h>

#define B_    32768
#define C_    64
#define D_    8
#define K15_  15
#define K16_  16
#define OUT_  512

typedef _Float16 half4v __attribute__((ext_vector_type(4)));
typedef _Float16 half8  __attribute__((ext_vector_type(8)));

// workspace layout (bytes)
#define AMAP_OFF  0
#define AMAP_SZ   32768                  // uint8 argmax per 15-bit code
#define S64_OFF   32768                  // fp64 S, k-major: S64[c][k][d]
#define S64_SZ    (64 * 15 * 8 * 8)      // 61440
#define T64_OFF   (S64_OFF + S64_SZ)     // 94208
#define T64_SZ    (64 * 15 * 8)          // 7680
#define IDX_OFF   (T64_OFF + T64_SZ)     // 101888
#define IDX_SZ    (B_ * C_)              // 2 MB. pairs mode: idxo unused ->
                                         // region reused for S32/T32 (fp32,
                                         // k-major) so WS_NEED is unchanged.
#define S32_SZ    (64 * 15 * 8 * 4)      // 30720
#define PCT_OFF   (IDX_OFF + IDX_SZ)     // 2199040
#define PCT_SZ    (B_ * 32)              // 1 MB: pcT[p][rg][tr][i]
#define PTAB_OFF  (PCT_OFF + PCT_SZ)     // 3247616 (16B aligned)
#define PTAB_SZ   (32 * 32 * 256 * 16 * 2) // 8388608: P5[p][jc][q][16] fp16
#define WS_NEED   ((size_t)PTAB_OFF + PTAB_SZ)

// global_load_lds, width 16 B: LDS dest is wave-uniform base + lane*16
// (m104/m173) -> LDS layout must be linear in lane order.
__device__ __forceinline__ void gld_lds16(const void* g, void* l) {
    __builtin_amdgcn_global_load_lds(
        (const __attribute__((address_space(1))) void*)g,
        (__attribute__((address_space(3))) void*)l, 16, 0, 0);
}

// ---------------------------------------------------------------------------
// k_setup (fused): 2048 blocks write P5 (j-first layout, fully coalesced
// 16B stores); blocks 0..127 also compute amap; block 128 builds S64/T64
// (+ S32/T32 fp32 copies when do_pairs).
// P5 half-index: ((p*32 + jc)*256 + q)*16 + e   (q = (t0<<4)|t1)
// ---------------------------------------------------------------------------
__global__ __launch_bounds__(256) void k_setup(const float* __restrict__ LUT,
                                               const float* __restrict__ H,
                                               const float* __restrict__ S,
                                               const float* __restrict__ T,
                                               _Float16* __restrict__ P5,
                                               uint8_t* __restrict__ amap,
                                               double* __restrict__ S64,
                                               double* __restrict__ T64,
                                               float* __restrict__ S32,
                                               float* __restrict__ T32,
                                               int do_pairs) {
    int gid = blockIdx.x * 256 + threadIdx.x;

    if (do_pairs) {
        // gid bits: [p:5][jc:5][q:8][e8:1] -> write offset = gid*8 halfs
        int e8 = gid & 1;
        int q = (gid >> 1) & 255;
        int jc = (gid >> 9) & 31;
        int p = gid >> 14;
        int t0 = q >> 4;
        int t1 = q & 15;
        int j0 = jc * 16 + e8 * 8;
        const float* u = LUT + (size_t)((2 * p) * 16 + t0) * 512 + j0;
        const float* v = LUT + (size_t)((2 * p + 1) * 16 + t1) * 512 + j0;
        float4 u0 = ((const float4*)u)[0];
        float4 u1 = ((const float4*)u)[1];
        float4 v0 = ((const float4*)v)[0];
        float4 v1 = ((const float4*)v)[1];
        half8 w;
        w[0] = (_Float16)(u0.x + v0.x);
        w[1] = (_Float16)(u0.y + v0.y);
        w[2] = (_Float16)(u0.z + v0.z);
        w[3] = (_Float16)(u0.w + v0.w);
        w[4] = (_Float16)(u1.x + v1.x);
        w[5] = (_Float16)(u1.y + v1.y);
        w[6] = (_Float16)(u1.z + v1.z);
        w[7] = (_Float16)(u1.w + v1.w);
        *(half8*)(P5 + (size_t)gid * 8) = w;
    }

    if (blockIdx.x < 128) {
        int code = gid;
        double h[K16_];
#pragma unroll
        for (int j = 0; j < K16_; ++j) h[j] = 0.0;
#pragma unroll
        for (int k = 0; k < K15_; ++k) {
            double s = ((code >> k) & 1) ? 1.0 : -1.0;
#pragma unroll
            for (int j = 0; j < K16_; ++j) h[j] += s * (double)H[k * K16_ + j];
        }
        double best = h[0];
        int bi = 0;
#pragma unroll
        for (int j = 1; j < K16_; ++j) {
            if (h[j] > best) { best = h[j]; bi = j; }
        }
        amap[code] = (uint8_t)bi;
    } else if (blockIdx.x == 128) {
        for (int i = threadIdx.x; i < 64 * 15 * 8; i += 256) {
            int c = i / 120;
            int r = i - c * 120;  // r = k*8 + d
            int k = r >> 3;
            int d = r & 7;
            float sv = S[c * 120 + d * 15 + k];
            S64[i] = (double)sv;
            if (do_pairs) S32[i] = sv;
        }
        for (int i = threadIdx.x; i < 64 * 15; i += 256) {
            T64[i] = (double)T[i];
            if (do_pairs) T32[i] = T[i];
        }
    }
}

// ---------------------------------------------------------------------------
// k_codes2: block = 256 thr (4 waves), 64 batches per block.
// Stage x into LDS transposed, wave<->channel, lane<->batch: S/T wave-uniform
// scalar loads. FAST=1: fp32 dot products (2x VALU rate of fp64) with fp64
// rescue when min_k |p_k| < EPS (fp32 err bound ~1e-5, EPS=1e-4 -> codes
// bit-identical to the all-fp64 version; rescue rate ~5e-4/channel). FAST=1
// also skips the idxo store (unused in pairs mode).
// Writes transposed pair codes pcT[p][rg=row>>10][tr=row&127][i=(row&1023)>>7].
// ---------------------------------------------------------------------------
#define XSTRIDE 585   // odd -> conflict-free
template <int FAST>
__global__ __launch_bounds__(256) void k_codes2(const float* __restrict__ x,
                                                const double* __restrict__ S64,
                                                const double* __restrict__ T64,
                                                const float* __restrict__ S32,
                                                const float* __restrict__ T32,
                                                const uint8_t* __restrict__ amap,
                                                uint8_t* __restrict__ idxo,
                                                uint8_t* __restrict__ pcT) {
    __shared__ float xls[32 * XSTRIDE];
    __shared__ uint8_t idsh[64 * 68];

    int b0 = blockIdx.x * 64;
    int lane = threadIdx.x & 63;
    int wv = __builtin_amdgcn_readfirstlane(threadIdx.x >> 6);

    for (int half = 0; half < 2; ++half) {
        __syncthreads();
#pragma unroll
        for (int t = 0; t < 16; ++t) {
            int e = t * 256 + threadIdx.x;
            int b = e >> 6;
            int j4 = e & 63;
            float4 v = ((const float4*)(x + (size_t)(b0 + b) * 512 +
                                        half * 256))[j4];
            int cl = j4 >> 1;
            int d0 = (j4 & 1) * 4;
            float* dst = &xls[cl * XSTRIDE + b * 9 + d0];
            dst[0] = v.x; dst[1] = v.y; dst[2] = v.z; dst[3] = v.w;
        }
        __syncthreads();
        for (int i = 0; i < 8; ++i) {
            int cl = wv + i * 4;                 // wave-uniform
            int c = half * 32 + cl;
            unsigned code = 0;
            if (FAST) {
                const float* Sc = S32 + c * 120;  // k-major: Sc[k*8+d]
                const float* Tc = T32 + c * 15;
                float xf[8];
#pragma unroll
                for (int d = 0; d < 8; ++d)
                    xf[d] = xls[cl * XSTRIDE + lane * 9 + d];
                float pmin = 3.0e38f;
#pragma unroll
                for (int k = 0; k < K15_; ++k) {
                    float p = -Tc[k];
#pragma unroll
                    for (int d = 0; d < 8; ++d)
                        p = fmaf(xf[d], Sc[k * 8 + d], p);
                    code |= (p > 0.f) ? (1u << k) : 0u;
                    pmin = fminf(pmin, fabsf(p));
                }
                if (pmin < 1e-4f) {  // rare: redo channel in fp64
                    const double* Sd = S64 + c * 120;
                    const double* Td = T64 + c * 15;
                    code = 0;
#pragma unroll
                    for (int k = 0; k < K15_; ++k) {
                        double p = -Td[k];
#pragma unroll
                        for (int d = 0; d < 8; ++d)
                            p = fma((double)xf[d], Sd[k * 8 + d], p);
                        code |= (p > 0.0) ? (1u << k) : 0u;
                    }
                }
            } else {
                const double* Sc = S64 + c * 120;  // k-major: Sc[k*8+d]
                const double* Tc = T64 + c * 15;
                double xd[8];
#pragma unroll
                for (int d = 0; d < 8; ++d)
                    xd[d] = (double)xls[cl * XSTRIDE + lane * 9 + d];
#pragma unroll
                for (int k = 0; k < K15_; ++k) {
                    double p = -Tc[k];
#pragma unroll
                    for (int d = 0; d < 8; ++d)
                        p = fma(xd[d], Sc[k * 8 + d], p);
                    code |= (p > 0.0) ? (1u << k) : 0u;
                }
            }
            idsh[lane * 68 + c] = amap[code];
        }
    }
    __syncthreads();

    int bb = threadIdx.x >> 2;
    int q = threadIdx.x & 3;
    if (!FAST) {
        uint32_t w0 = *(const uint32_t*)&idsh[bb * 68 + q * 16 + 0];
        uint32_t w1 = *(const uint32_t*)&idsh[bb * 68 + q * 16 + 4];
        uint32_t w2 = *(const uint32_t*)&idsh[bb * 68 + q * 16 + 8];
        uint32_t w3 = *(const uint32_t*)&idsh[bb * 68 + q * 16 + 12];
        uint32_t* o = (uint32_t*)(idxo + (size_t)(b0 + bb) * 64 + q * 16);
        o[0] = w0; o[1] = w1; o[2] = w2; o[3] = w3;
    }
    {
        int row = b0 + bb;
        int rg = row >> 10;
        int tr = row & 127;
        int i_ = (row & 1023) >> 7;
        uint8_t* base = pcT + rg * 1024 + tr * 8 + i_;
#pragma unroll
        for (int pi = 0; pi < 8; ++pi) {
            int p = q * 8 + pi;
            uint8_t byte = (uint8_t)((idsh[bb * 68 + 2 * p] << 4) |
                                     idsh[bb * 68 + 2 * p + 1]);
            base[p * 32768] = byte;
        }
    }
}

// ---------------------------------------------------------------------------
// k_main8: streaming-staged gather, v4.
// Changes vs k_main7 (which was LDS-pipe throughput bound; conflicts
// structural at 8.54e6):
//   * slab staged via global_load_lds (width 16): removes 2 ds_write_b128
//     wave-instrs/thread/pair (~20K cy/CU off the saturated LDS issue path)
//     and the g0/g1 VGPR round-trip. Requires LINEAR LDS dest (wave-uniform
//     base + lane*16, m104) -> slab is unpadded [256][16 halfs] (32 B rows).
//   * read-side quad index becomes (2*ci + tc)&7: even/odd lanes split over
//     even/odd quads, two independent (32 balls -> 4 bins) draws, E[max]
//     ~11.5 cy -- statistically same conflict cost as the 48B layout.
//   * LDS 2x8 KB -> 8 resident blocks/CU; launch_bounds(256,8).
// Pipeline per pair: barrier (compiler's vmcnt(0) drain = slab[p] landed) ->
// issue loads for p+1 into other buffer + cw prefetch -> gather p. Loads get
// the whole gather (~200+ cy) to land; P5 slab is L2-resident (jc->XCD pin:
// blocks sharing jc are blk = jc+32k -> XCD jc%8).
// ---------------------------------------------------------------------------
__global__ __launch_bounds__(256, 8) void k_main8(const uint8_t* __restrict__ pcT,
                                                  const _Float16* __restrict__ P5,
                                                  float* __restrict__ out) {
    __shared__ alignas(16) _Float16 slab[2][256 * 16];  // 8 KB per buffer, linear

    int rg5 = blockIdx.x >> 5;   // 0..63, owns rows rg5*512 + i*128 + tr
    int jc = blockIdx.x & 31;
    int t = threadIdx.x;
    int tc = t & 1;        // which 8-half piece of the 16-half chunk
    int tr = t >> 1;       // 0..127
    int lane = t & 63;
    int wv = __builtin_amdgcn_readfirstlane(t >> 6);  // wave-uniform

    // pcT[p][rg][tr][i_]: for row = rg5*512 + i*128 + tr:
    //   rg = rg5>>1, i_ = (rg5&1)*4 + i  -> 4 consecutive bytes
    const uint8_t* cbase = pcT + (rg5 >> 1) * 1024 + tr * 8 + (rg5 & 1) * 4;

    float acc[4][8];
#pragma unroll
    for (int i = 0; i < 4; ++i)
#pragma unroll
        for (int e = 0; e < 8; ++e) acc[i][e] = 0.f;

    // staging: wave wv covers halfs [wv*512 + lane*8) and [+2048) of the
    // 4096-half slab; global src mirrors the linear LDS dest exactly.
    int hoff = wv * 512 + lane * 8;

    // prologue: issue p=0 stage + load cw0
    {
        const _Float16* g = P5 + (size_t)jc * 4096 + hoff;
        gld_lds16(g, &slab[0][wv * 512]);
        gld_lds16(g + 2048, &slab[0][wv * 512 + 2048]);
    }
    uint32_t cw = *(const uint32_t*)cbase;
    uint32_t cwn = 0;

    for (int p = 0; p < 32; ++p) {
        // compiler emits s_waitcnt vmcnt(0) before s_barrier -> slab[p&1]
        // landed; barrier also fences gather(p-1) vs stage(p+1) (same buf).
        __syncthreads();

        if (p < 31) {
            const _Float16* g =
                P5 + (size_t)((p + 1) * 32 + jc) * 4096 + hoff;
            _Float16* d = &slab[(p + 1) & 1][wv * 512];
            gld_lds16(g, d);
            gld_lds16(g + 2048, d + 2048);
            cwn = *(const uint32_t*)(cbase + (size_t)(p + 1) * 32768);
        }

        const _Float16* rb = &slab[p & 1][0] + tc * 8;
        uint32_t cw_cur = cw;
#pragma unroll
        for (int i = 0; i < 4; ++i) {
            int ci = (int)((cw_cur >> (8 * i)) & 0xFF);
            half8 v = *(const half8*)(rb + ci * 16);  // one ds_read_b128
#pragma unroll
            for (int e = 0; e < 8; ++e)
                acc[i][e] = fmaf((float)v[e], 1.0f, acc[i][e]);
        }
        cw = cwn;
    }

#pragma unroll
    for (int i = 0; i < 4; ++i) {
        int row = rg5 * 512 + i * 128 + tr;
        float* o = out + (size_t)row * 512 + jc * 16 + tc * 8;
        float4 w0;
        w0.x = acc[i][0]; w0.y = acc[i][1]; w0.z = acc[i][2]; w0.w = acc[i][3];
        float4 w1;
        w1.x = acc[i][4]; w1.y = acc[i][5]; w1.z = acc[i][6]; w1.w = acc[i][7];
        ((float4*)o)[0] = w0;
        ((float4*)o)[1] = w1;
    }
}

// Fallback (small ws): direct 64-channel gather from fp32 LUT.
__global__ __launch_bounds__(256) void k_main_direct(const uint8_t* __restrict__ idx,
                                                     const float* __restrict__ LUT,
                                                     float* __restrict__ out) {
    int j4 = threadIdx.x & 127;
    int sub = threadIdx.x >> 7;
    int b0 = blockIdx.x * 16 + sub * 8;
    const float4* L4 = (const float4*)LUT;
    for (int r = 0; r < 8; ++r) {
        int b = b0 + r;
        const uint32_t* iw = (const uint32_t*)(idx + (size_t)b * 64);
        float4 acc;
        acc.x = 0.f; acc.y = 0.f; acc.z = 0.f; acc.w = 0.f;
#pragma unroll
        for (int i = 0; i < 16; ++i) {
            uint32_t w = __builtin_amdgcn_readfirstlane(iw[i]);
#pragma unroll
            for (int t = 0; t < 4; ++t) {
                int c = i * 4 + t;
                uint32_t codev = (w >> (8 * t)) & 0xFu;
                float4 v = L4[(size_t)(c * 16 + codev) * 128 + j4];
                acc.x += v.x; acc.y += v.y; acc.z += v.z; acc.w += v.w;
            }
        }
        ((float4*)(out + (size_t)b * 512))[j4] = acc;
    }
}

extern "C" void kernel_launch(void* const* d_in, const int* in_sizes, int n_in,
                              void* d_out, int out_size, void* d_ws, size_t ws_size,
                              hipStream_t stream) {
    const float* x   = (const float*)d_in[0];
    const float* S   = (const float*)d_in[1];
    const float* H   = (const float*)d_in[2];
    const float* T   = (const float*)d_in[3];
    const float* LUT = (const float*)d_in[4];
    float* out = (float*)d_out;

    uint8_t* ws = (uint8_t*)d_ws;
    uint8_t* amap = ws + AMAP_OFF;
    double* S64   = (double*)(ws + S64_OFF);
    double* T64   = (double*)(ws + T64_OFF);
    uint8_t* idxb = ws + IDX_OFF;                  // fallback mode only
    float* S32    = (float*)(ws + IDX_OFF);        // pairs mode only
    float* T32    = (float*)(ws + IDX_OFF + S32_SZ);
    uint8_t* pcTb = ws + PCT_OFF;
    _Float16* P5  = (_Float16*)(ws + PTAB_OFF);

    bool use_pairs = ws_size >= WS_NEED;

    hipLaunchKernelGGL(k_setup, dim3(use_pairs ? 2048 : 129), dim3(256), 0,
                       stream, LUT, H, S, T, P5, amap, S64, T64, S32, T32,
                       use_pairs ? 1 : 0);
    if (use_pairs) {
        hipLaunchKernelGGL((k_codes2<1>), dim3(B_ / 64), dim3(256), 0, stream,
                           x, S64, T64, S32, T32, amap, idxb, pcTb);
        hipLaunchKernelGGL(k_main8, dim3(2048), dim3(256), 0, stream,
                           pcTb, P5, out);
    } else {
        hipLaunchKernelGGL((k_codes2<0>), dim3(B_ / 64), dim3(256), 0, stream,
                           x, S64, T64, S32, T32, amap, idxb, pcTb);
        hipLaunchKernelGGL(k_main_direct, dim3(B_ / 16), dim3(256), 0, stream,
                           idxb, LUT, out);
    }
}

// Round 4
// 182.568 us; speedup vs baseline: 1.0398x; 1.0294x over previous
//
#include <hip/hip_runtime.h>
#include <stdint.h>

#define B_    32768
#define C_    64
#define D_    8
#define K15_  15
#define K16_  16
#define OUT_  512

typedef _Float16 half4v __attribute__((ext_vector_type(4)));
typedef _Float16 half8  __attribute__((ext_vector_type(8)));

// workspace layout (bytes)
#define AMAP_OFF  0
#define AMAP_SZ   32768                  // uint8 argmax per 15-bit code
#define S64_OFF   32768                  // fp64 S, k-major: S64[c][k][d]
#define S64_SZ    (64 * 15 * 8 * 8)      // 61440
#define T64_OFF   (S64_OFF + S64_SZ)     // 94208
#define T64_SZ    (64 * 15 * 8)          // 7680
#define IDX_OFF   (T64_OFF + T64_SZ)     // 101888
#define IDX_SZ    (B_ * C_)              // 2 MB. pairs mode: idxo unused ->
                                         // region reused for S32/T32 (fp32,
                                         // k-major) so WS_NEED is unchanged.
#define S32_SZ    (64 * 15 * 8 * 4)      // 30720
#define PCT_OFF   (IDX_OFF + IDX_SZ)     // 2199040
#define PCT_SZ    (B_ * 32)              // 1 MB: pcT[p][rg][tr][i]
#define PTAB_OFF  (PCT_OFF + PCT_SZ)     // 3247616 (16B aligned)
#define PTAB_SZ   (32 * 32 * 256 * 16 * 2) // 8388608: P5[p][jc][q][16] fp16
#define WS_NEED   ((size_t)PTAB_OFF + PTAB_SZ)

// global_load_lds, width 16 B: LDS dest is wave-uniform base + lane*16
// (m104/m173) -> LDS layout must be linear in lane order.
__device__ __forceinline__ void gld_lds16(const void* g, void* l) {
    __builtin_amdgcn_global_load_lds(
        (const __attribute__((address_space(1))) void*)g,
        (__attribute__((address_space(3))) void*)l, 16, 0, 0);
}

// ---------------------------------------------------------------------------
// k_setup (fused): 2048 blocks write P5 (j-first layout, fully coalesced
// 16B stores); blocks 0..127 also compute amap; block 128 builds S64/T64
// (+ S32/T32 fp32 copies when do_pairs).
// P5 half-index: ((p*32 + jc)*256 + q)*16 + e   (q = (t0<<4)|t1)
// ---------------------------------------------------------------------------
__global__ __launch_bounds__(256) void k_setup(const float* __restrict__ LUT,
                                               const float* __restrict__ H,
                                               const float* __restrict__ S,
                                               const float* __restrict__ T,
                                               _Float16* __restrict__ P5,
                                               uint8_t* __restrict__ amap,
                                               double* __restrict__ S64,
                                               double* __restrict__ T64,
                                               float* __restrict__ S32,
                                               float* __restrict__ T32,
                                               int do_pairs) {
    int gid = blockIdx.x * 256 + threadIdx.x;

    if (do_pairs) {
        // gid bits: [p:5][jc:5][q:8][e8:1] -> write offset = gid*8 halfs
        int e8 = gid & 1;
        int q = (gid >> 1) & 255;
        int jc = (gid >> 9) & 31;
        int p = gid >> 14;
        int t0 = q >> 4;
        int t1 = q & 15;
        int j0 = jc * 16 + e8 * 8;
        const float* u = LUT + (size_t)((2 * p) * 16 + t0) * 512 + j0;
        const float* v = LUT + (size_t)((2 * p + 1) * 16 + t1) * 512 + j0;
        float4 u0 = ((const float4*)u)[0];
        float4 u1 = ((const float4*)u)[1];
        float4 v0 = ((const float4*)v)[0];
        float4 v1 = ((const float4*)v)[1];
        half8 w;
        w[0] = (_Float16)(u0.x + v0.x);
        w[1] = (_Float16)(u0.y + v0.y);
        w[2] = (_Float16)(u0.z + v0.z);
        w[3] = (_Float16)(u0.w + v0.w);
        w[4] = (_Float16)(u1.x + v1.x);
        w[5] = (_Float16)(u1.y + v1.y);
        w[6] = (_Float16)(u1.z + v1.z);
        w[7] = (_Float16)(u1.w + v1.w);
        *(half8*)(P5 + (size_t)gid * 8) = w;
    }

    if (blockIdx.x < 128) {
        int code = gid;
        double h[K16_];
#pragma unroll
        for (int j = 0; j < K16_; ++j) h[j] = 0.0;
#pragma unroll
        for (int k = 0; k < K15_; ++k) {
            double s = ((code >> k) & 1) ? 1.0 : -1.0;
#pragma unroll
            for (int j = 0; j < K16_; ++j) h[j] += s * (double)H[k * K16_ + j];
        }
        double best = h[0];
        int bi = 0;
#pragma unroll
        for (int j = 1; j < K16_; ++j) {
            if (h[j] > best) { best = h[j]; bi = j; }
        }
        amap[code] = (uint8_t)bi;
    } else if (blockIdx.x == 128) {
        for (int i = threadIdx.x; i < 64 * 15 * 8; i += 256) {
            int c = i / 120;
            int r = i - c * 120;  // r = k*8 + d
            int k = r >> 3;
            int d = r & 7;
            float sv = S[c * 120 + d * 15 + k];
            S64[i] = (double)sv;
            if (do_pairs) S32[i] = sv;
        }
        for (int i = threadIdx.x; i < 64 * 15; i += 256) {
            T64[i] = (double)T[i];
            if (do_pairs) T32[i] = T[i];
        }
    }
}

// ---------------------------------------------------------------------------
// k_codes3: block = 256 thr (4 waves), 64 batches per block.
// v2 was occupancy-starved (79 KB LDS -> 2 blocks/CU, VALUBusy 15%).
// Changes:
//   * 8 channels per round (8 rounds) -> xls 18.8 KB; +codesh 8.4 KB =
//     27.2 KB total -> 5 blocks/CU (20 waves, 2.5x TLP).
//   * rounds store the raw 15-bit code to LDS (codesh); ALL amap gathers
//     deferred to one end phase (16 independent loads/thread, pipelined)
//     which packs and writes pcT (FAST) / idxo (!FAST) directly.
// Numerics unchanged: fp32 dots + fp64 rescue when min|p| < 1e-4 (codes
// bit-identical to all-fp64).
// ---------------------------------------------------------------------------
#define XST2 587   // stage-write start banks cl*11+d0 all distinct; reads 2-way
template <int FAST>
__global__ __launch_bounds__(256, 5) void k_codes3(const float* __restrict__ x,
                                                   const double* __restrict__ S64,
                                                   const double* __restrict__ T64,
                                                   const float* __restrict__ S32,
                                                   const float* __restrict__ T32,
                                                   const uint8_t* __restrict__ amap,
                                                   uint8_t* __restrict__ idxo,
                                                   uint8_t* __restrict__ pcT) {
    __shared__ float xls[8 * XST2];          // 8 channels x 64 batches x 9
    __shared__ uint16_t codesh[64 * 66];     // [batch][channel], pad 66

    int b0 = blockIdx.x * 64;
    int lane = threadIdx.x & 63;
    int wv = __builtin_amdgcn_readfirstlane(threadIdx.x >> 6);

    for (int r = 0; r < 8; ++r) {  // channels r*8 .. r*8+7
        __syncthreads();
#pragma unroll
        for (int t2 = 0; t2 < 4; ++t2) {
            int e = t2 * 256 + threadIdx.x;  // 0..1023
            int b = e >> 4;
            int j4 = e & 15;
            float4 v = ((const float4*)(x + (size_t)(b0 + b) * 512 +
                                        r * 64))[j4];
            int cl = j4 >> 1;
            int d0 = (j4 & 1) * 4;
            float* dst = &xls[cl * XST2 + b * 9 + d0];
            dst[0] = v.x; dst[1] = v.y; dst[2] = v.z; dst[3] = v.w;
        }
        __syncthreads();
#pragma unroll
        for (int i = 0; i < 2; ++i) {
            int cl = wv + i * 4;                 // wave-uniform
            int c = r * 8 + cl;
            unsigned code = 0;
            if (FAST) {
                const float* Sc = S32 + c * 120;  // k-major: Sc[k*8+d]
                const float* Tc = T32 + c * 15;
                float xf[8];
#pragma unroll
                for (int d = 0; d < 8; ++d)
                    xf[d] = xls[cl * XST2 + lane * 9 + d];
                float pmin = 3.0e38f;
#pragma unroll
                for (int k = 0; k < K15_; ++k) {
                    float p = -Tc[k];
#pragma unroll
                    for (int d = 0; d < 8; ++d)
                        p = fmaf(xf[d], Sc[k * 8 + d], p);
                    code |= (p > 0.f) ? (1u << k) : 0u;
                    pmin = fminf(pmin, fabsf(p));
                }
                if (pmin < 1e-4f) {  // rare: redo channel in fp64
                    const double* Sd = S64 + c * 120;
                    const double* Td = T64 + c * 15;
                    code = 0;
#pragma unroll
                    for (int k = 0; k < K15_; ++k) {
                        double p = -Td[k];
#pragma unroll
                        for (int d = 0; d < 8; ++d)
                            p = fma((double)xf[d], Sd[k * 8 + d], p);
                        code |= (p > 0.0) ? (1u << k) : 0u;
                    }
                }
            } else {
                const double* Sc = S64 + c * 120;  // k-major: Sc[k*8+d]
                const double* Tc = T64 + c * 15;
                double xd[8];
#pragma unroll
                for (int d = 0; d < 8; ++d)
                    xd[d] = (double)xls[cl * XST2 + lane * 9 + d];
#pragma unroll
                for (int k = 0; k < K15_; ++k) {
                    double p = -Tc[k];
#pragma unroll
                    for (int d = 0; d < 8; ++d)
                        p = fma(xd[d], Sc[k * 8 + d], p);
                    code |= (p > 0.0) ? (1u << k) : 0u;
                }
            }
            codesh[lane * 66 + c] = (uint16_t)code;
        }
    }
    __syncthreads();

    // End phase: thread (bb,q) owns batch bb, channels q*16..q*16+15.
    int bb = threadIdx.x >> 2;
    int q = threadIdx.x & 3;
    uint16_t cds[16];
#pragma unroll
    for (int j = 0; j < 4; ++j) {
        // 4 consecutive uint16 codes per b64 read (2-way bank alias, free)
        *(ulong1*)&cds[j * 4] =
            *(const ulong1*)&codesh[bb * 66 + q * 16 + j * 4];
    }
    uint8_t ids[16];
#pragma unroll
    for (int j = 0; j < 16; ++j) ids[j] = amap[cds[j]];  // 16 indep gathers

    if (FAST) {
        int row = b0 + bb;
        int rg = row >> 10;
        int tr = row & 127;
        int i_ = (row & 1023) >> 7;
        uint8_t* base = pcT + rg * 1024 + tr * 8 + i_;
#pragma unroll
        for (int pi = 0; pi < 8; ++pi) {
            uint8_t byte = (uint8_t)((ids[2 * pi] << 4) | ids[2 * pi + 1]);
            base[(q * 8 + pi) * 32768] = byte;
        }
    } else {
        uint32_t w[4];
#pragma unroll
        for (int j = 0; j < 4; ++j)
            w[j] = (uint32_t)ids[4 * j] | ((uint32_t)ids[4 * j + 1] << 8) |
                   ((uint32_t)ids[4 * j + 2] << 16) |
                   ((uint32_t)ids[4 * j + 3] << 24);
        uint32_t* o = (uint32_t*)(idxo + (size_t)(b0 + bb) * 64 + q * 16);
        o[0] = w[0]; o[1] = w[1]; o[2] = w[2]; o[3] = w[3];
    }
}

// ---------------------------------------------------------------------------
// k_main8: streaming-staged gather, v4 (unchanged this round).
// Slab staged via global_load_lds (width 16), linear [256][16] fp16 rows;
// double-buffered 2x8 KB -> 8 blocks/CU; prefetch issued right after the
// barrier; compiler's vmcnt(0)-before-s_barrier is the drain we need.
// jc->XCD pinning: blocks sharing jc are blk = jc+32k -> same XCD L2.
// ---------------------------------------------------------------------------
__global__ __launch_bounds__(256, 8) void k_main8(const uint8_t* __restrict__ pcT,
                                                  const _Float16* __restrict__ P5,
                                                  float* __restrict__ out) {
    __shared__ alignas(16) _Float16 slab[2][256 * 16];  // 8 KB per buffer, linear

    int rg5 = blockIdx.x >> 5;   // 0..63, owns rows rg5*512 + i*128 + tr
    int jc = blockIdx.x & 31;
    int t = threadIdx.x;
    int tc = t & 1;        // which 8-half piece of the 16-half chunk
    int tr = t >> 1;       // 0..127
    int lane = t & 63;
    int wv = __builtin_amdgcn_readfirstlane(t >> 6);  // wave-uniform

    // pcT[p][rg][tr][i_]: for row = rg5*512 + i*128 + tr:
    //   rg = rg5>>1, i_ = (rg5&1)*4 + i  -> 4 consecutive bytes
    const uint8_t* cbase = pcT + (rg5 >> 1) * 1024 + tr * 8 + (rg5 & 1) * 4;

    float acc[4][8];
#pragma unroll
    for (int i = 0; i < 4; ++i)
#pragma unroll
        for (int e = 0; e < 8; ++e) acc[i][e] = 0.f;

    // staging: wave wv covers halfs [wv*512 + lane*8) and [+2048) of the
    // 4096-half slab; global src mirrors the linear LDS dest exactly.
    int hoff = wv * 512 + lane * 8;

    // prologue: issue p=0 stage + load cw0
    {
        const _Float16* g = P5 + (size_t)jc * 4096 + hoff;
        gld_lds16(g, &slab[0][wv * 512]);
        gld_lds16(g + 2048, &slab[0][wv * 512 + 2048]);
    }
    uint32_t cw = *(const uint32_t*)cbase;
    uint32_t cwn = 0;

    for (int p = 0; p < 32; ++p) {
        // compiler emits s_waitcnt vmcnt(0) before s_barrier -> slab[p&1]
        // landed; barrier also fences gather(p-1) vs stage(p+1) (same buf).
        __syncthreads();

        if (p < 31) {
            const _Float16* g =
                P5 + (size_t)((p + 1) * 32 + jc) * 4096 + hoff;
            _Float16* d = &slab[(p + 1) & 1][wv * 512];
            gld_lds16(g, d);
            gld_lds16(g + 2048, d + 2048);
            cwn = *(const uint32_t*)(cbase + (size_t)(p + 1) * 32768);
        }

        const _Float16* rb = &slab[p & 1][0] + tc * 8;
        uint32_t cw_cur = cw;
#pragma unroll
        for (int i = 0; i < 4; ++i) {
            int ci = (int)((cw_cur >> (8 * i)) & 0xFF);
            half8 v = *(const half8*)(rb + ci * 16);  // one ds_read_b128
#pragma unroll
            for (int e = 0; e < 8; ++e)
                acc[i][e] = fmaf((float)v[e], 1.0f, acc[i][e]);
        }
        cw = cwn;
    }

#pragma unroll
    for (int i = 0; i < 4; ++i) {
        int row = rg5 * 512 + i * 128 + tr;
        float* o = out + (size_t)row * 512 + jc * 16 + tc * 8;
        float4 w0;
        w0.x = acc[i][0]; w0.y = acc[i][1]; w0.z = acc[i][2]; w0.w = acc[i][3];
        float4 w1;
        w1.x = acc[i][4]; w1.y = acc[i][5]; w1.z = acc[i][6]; w1.w = acc[i][7];
        ((float4*)o)[0] = w0;
        ((float4*)o)[1] = w1;
    }
}

// Fallback (small ws): direct 64-channel gather from fp32 LUT.
__global__ __launch_bounds__(256) void k_main_direct(const uint8_t* __restrict__ idx,
                                                     const float* __restrict__ LUT,
                                                     float* __restrict__ out) {
    int j4 = threadIdx.x & 127;
    int sub = threadIdx.x >> 7;
    int b0 = blockIdx.x * 16 + sub * 8;
    const float4* L4 = (const float4*)LUT;
    for (int r = 0; r < 8; ++r) {
        int b = b0 + r;
        const uint32_t* iw = (const uint32_t*)(idx + (size_t)b * 64);
        float4 acc;
        acc.x = 0.f; acc.y = 0.f; acc.z = 0.f; acc.w = 0.f;
#pragma unroll
        for (int i = 0; i < 16; ++i) {
            uint32_t w = __builtin_amdgcn_readfirstlane(iw[i]);
#pragma unroll
            for (int t = 0; t < 4; ++t) {
                int c = i * 4 + t;
                uint32_t codev = (w >> (8 * t)) & 0xFu;
                float4 v = L4[(size_t)(c * 16 + codev) * 128 + j4];
                acc.x += v.x; acc.y += v.y; acc.z += v.z; acc.w += v.w;
            }
        }
        ((float4*)(out + (size_t)b * 512))[j4] = acc;
    }
}

extern "C" void kernel_launch(void* const* d_in, const int* in_sizes, int n_in,
                              void* d_out, int out_size, void* d_ws, size_t ws_size,
                              hipStream_t stream) {
    const float* x   = (const float*)d_in[0];
    const float* S   = (const float*)d_in[1];
    const float* H   = (const float*)d_in[2];
    const float* T   = (const float*)d_in[3];
    const float* LUT = (const float*)d_in[4];
    float* out = (float*)d_out;

    uint8_t* ws = (uint8_t*)d_ws;
    uint8_t* amap = ws + AMAP_OFF;
    double* S64   = (double*)(ws + S64_OFF);
    double* T64   = (double*)(ws + T64_OFF);
    uint8_t* idxb = ws + IDX_OFF;                  // fallback mode only
    float* S32    = (float*)(ws + IDX_OFF);        // pairs mode only
    float* T32    = (float*)(ws + IDX_OFF + S32_SZ);
    uint8_t* pcTb = ws + PCT_OFF;
    _Float16* P5  = (_Float16*)(ws + PTAB_OFF);

    bool use_pairs = ws_size >= WS_NEED;

    hipLaunchKernelGGL(k_setup, dim3(use_pairs ? 2048 : 129), dim3(256), 0,
                       stream, LUT, H, S, T, P5, amap, S64, T64, S32, T32,
                       use_pairs ? 1 : 0);
    if (use_pairs) {
        hipLaunchKernelGGL((k_codes3<1>), dim3(B_ / 64), dim3(256), 0, stream,
                           x, S64, T64, S32, T32, amap, idxb, pcTb);
        hipLaunchKernelGGL(k_main8, dim3(2048), dim3(256), 0, stream,
                           pcTb, P5, out);
    } else {
        hipLaunchKernelGGL((k_codes3<0>), dim3(B_ / 64), dim3(256), 0, stream,
                           x, S64, T64, S32, T32, amap, idxb, pcTb);
        hipLaunchKernelGGL(k_main_direct, dim3(B_ / 16), dim3(256), 0, stream,
                           idxb, LUT, out);
    }
}

// Round 5
// 174.405 us; speedup vs baseline: 1.0885x; 1.0468x over previous
//
#include <hip/hip_runtime.h>
#include <stdint.h>

#define B_    32768
#define C_    64
#define D_    8
#define K15_  15
#define K16_  16
#define OUT_  512

typedef _Float16 half4v __attribute__((ext_vector_type(4)));
typedef _Float16 half8  __attribute__((ext_vector_type(8)));

// workspace layout (bytes)
#define AMAP_OFF  0
#define AMAP_SZ   32768                  // uint8 argmax per 15-bit code
#define S64_OFF   32768                  // fp64 S, k-major: S64[c][k][d]
#define S64_SZ    (64 * 15 * 8 * 8)      // 61440
#define T64_OFF   (S64_OFF + S64_SZ)     // 94208
#define T64_SZ    (64 * 15 * 8)          // 7680
#define IDX_OFF   (T64_OFF + T64_SZ)     // 101888
#define IDX_SZ    (B_ * C_)              // 2 MB. pairs mode: idxo unused ->
                                         // region reused for S32/T32 (fp32,
                                         // k-major) so WS_NEED is unchanged.
#define S32_SZ    (64 * 15 * 8 * 4)      // 30720
#define PCT_OFF   (IDX_OFF + IDX_SZ)     // 2199040
#define PCT_SZ    (B_ * 32)              // 1 MB: pcT[p][rg][tr][i]
#define PTAB_OFF  (PCT_OFF + PCT_SZ)     // 3247616 (16B aligned)
#define PTAB_SZ   (32 * 32 * 256 * 16 * 2) // 8388608: P5[p][jc][q][16] fp16
#define WS_NEED   ((size_t)PTAB_OFF + PTAB_SZ)

// global_load_lds, width 16 B: LDS dest is wave-uniform base + lane*16
// (m104/m173) -> LDS layout must be linear in lane order.
__device__ __forceinline__ void gld_lds16(const void* g, void* l) {
    __builtin_amdgcn_global_load_lds(
        (const __attribute__((address_space(1))) void*)g,
        (__attribute__((address_space(3))) void*)l, 16, 0, 0);
}

// ---------------------------------------------------------------------------
// k_setup (fused): 2048 blocks write P5 (j-first layout, fully coalesced
// 16B stores); blocks 0..127 also compute amap; block 128 builds S64/T64
// (+ S32/T32 fp32 copies when do_pairs).
// P5 half-index: ((p*32 + jc)*256 + q)*16 + e   (q = (t0<<4)|t1)
// ---------------------------------------------------------------------------
__global__ __launch_bounds__(256) void k_setup(const float* __restrict__ LUT,
                                               const float* __restrict__ H,
                                               const float* __restrict__ S,
                                               const float* __restrict__ T,
                                               _Float16* __restrict__ P5,
                                               uint8_t* __restrict__ amap,
                                               double* __restrict__ S64,
                                               double* __restrict__ T64,
                                               float* __restrict__ S32,
                                               float* __restrict__ T32,
                                               int do_pairs) {
    int gid = blockIdx.x * 256 + threadIdx.x;

    if (do_pairs) {
        // gid bits: [p:5][jc:5][q:8][e8:1] -> write offset = gid*8 halfs
        int e8 = gid & 1;
        int q = (gid >> 1) & 255;
        int jc = (gid >> 9) & 31;
        int p = gid >> 14;
        int t0 = q >> 4;
        int t1 = q & 15;
        int j0 = jc * 16 + e8 * 8;
        const float* u = LUT + (size_t)((2 * p) * 16 + t0) * 512 + j0;
        const float* v = LUT + (size_t)((2 * p + 1) * 16 + t1) * 512 + j0;
        float4 u0 = ((const float4*)u)[0];
        float4 u1 = ((const float4*)u)[1];
        float4 v0 = ((const float4*)v)[0];
        float4 v1 = ((const float4*)v)[1];
        half8 w;
        w[0] = (_Float16)(u0.x + v0.x);
        w[1] = (_Float16)(u0.y + v0.y);
        w[2] = (_Float16)(u0.z + v0.z);
        w[3] = (_Float16)(u0.w + v0.w);
        w[4] = (_Float16)(u1.x + v1.x);
        w[5] = (_Float16)(u1.y + v1.y);
        w[6] = (_Float16)(u1.z + v1.z);
        w[7] = (_Float16)(u1.w + v1.w);
        *(half8*)(P5 + (size_t)gid * 8) = w;
    }

    if (blockIdx.x < 128) {
        int code = gid;
        double h[K16_];
#pragma unroll
        for (int j = 0; j < K16_; ++j) h[j] = 0.0;
#pragma unroll
        for (int k = 0; k < K15_; ++k) {
            double s = ((code >> k) & 1) ? 1.0 : -1.0;
#pragma unroll
            for (int j = 0; j < K16_; ++j) h[j] += s * (double)H[k * K16_ + j];
        }
        double best = h[0];
        int bi = 0;
#pragma unroll
        for (int j = 1; j < K16_; ++j) {
            if (h[j] > best) { best = h[j]; bi = j; }
        }
        amap[code] = (uint8_t)bi;
    } else if (blockIdx.x == 128) {
        for (int i = threadIdx.x; i < 64 * 15 * 8; i += 256) {
            int c = i / 120;
            int r = i - c * 120;  // r = k*8 + d
            int k = r >> 3;
            int d = r & 7;
            float sv = S[c * 120 + d * 15 + k];
            S64[i] = (double)sv;
            if (do_pairs) S32[i] = sv;
        }
        for (int i = threadIdx.x; i < 64 * 15; i += 256) {
            T64[i] = (double)T[i];
            if (do_pairs) T32[i] = T[i];
        }
    }
}

// ---------------------------------------------------------------------------
// k_codes4: block = (batch-group of 64, channel-half of 32). Grid 1024.
// v3 (k_codes3) was GRID-limited to 2 blocks/CU (512 blocks) -- the R4 LDS
// shrink raised the residency cap but not the supply. v4 splits channels
// across 2 blocks: 4 blocks/CU, and per-block serial rounds halve (8 -> 4).
// x reads are disjoint per block (column halves); pcT/idxo writes disjoint.
// Rounds store raw 15-bit codes to LDS; end phase reads 8 codes per thread
// with ONE ds_read_b128 (pad 40 -> 16B-aligned rows), does 8 independent
// amap gathers, packs and writes pcT (FAST) / idxo (!FAST).
// Numerics unchanged: fp32 dots + fp64 rescue when min|p| < 1e-4 (codes
// bit-identical to all-fp64).
// ---------------------------------------------------------------------------
#define XST2 587   // stage-write start banks cl*11+d0 all distinct; reads 2-way
#define CPAD 40    // uint16 row pad: 80B rows -> b128-aligned end-phase reads
template <int FAST>
__global__ __launch_bounds__(256, 4) void k_codes4(const float* __restrict__ x,
                                                   const double* __restrict__ S64,
                                                   const double* __restrict__ T64,
                                                   const float* __restrict__ S32,
                                                   const float* __restrict__ T32,
                                                   const uint8_t* __restrict__ amap,
                                                   uint8_t* __restrict__ idxo,
                                                   uint8_t* __restrict__ pcT) {
    __shared__ float xls[8 * XST2];              // 8 channels x 64 batches x 9
    __shared__ alignas(16) uint16_t codesh[64 * CPAD];  // [batch][local chan]

    int bg = blockIdx.x >> 1;        // batch group: rows bg*64 .. +63
    int hb = blockIdx.x & 1;         // channel half: channels hb*32 .. +31
    int b0 = bg * 64;
    int lane = threadIdx.x & 63;
    int wv = __builtin_amdgcn_readfirstlane(threadIdx.x >> 6);

    for (int r = 0; r < 4; ++r) {    // local channels r*8 .. r*8+7
        __syncthreads();
#pragma unroll
        for (int t2 = 0; t2 < 4; ++t2) {
            int e = t2 * 256 + threadIdx.x;  // 0..1023
            int b = e >> 4;
            int j4 = e & 15;
            float4 v = ((const float4*)(x + (size_t)(b0 + b) * 512 +
                                        hb * 256 + r * 64))[j4];
            int cl = j4 >> 1;
            int d0 = (j4 & 1) * 4;
            float* dst = &xls[cl * XST2 + b * 9 + d0];
            dst[0] = v.x; dst[1] = v.y; dst[2] = v.z; dst[3] = v.w;
        }
        __syncthreads();
#pragma unroll
        for (int i = 0; i < 2; ++i) {
            int cl = wv + i * 4;                 // wave-uniform, 0..7
            int c = hb * 32 + r * 8 + cl;        // global channel
            unsigned code = 0;
            if (FAST) {
                const float* Sc = S32 + c * 120;  // k-major: Sc[k*8+d]
                const float* Tc = T32 + c * 15;
                float xf[8];
#pragma unroll
                for (int d = 0; d < 8; ++d)
                    xf[d] = xls[cl * XST2 + lane * 9 + d];
                float pmin = 3.0e38f;
#pragma unroll
                for (int k = 0; k < K15_; ++k) {
                    float p = -Tc[k];
#pragma unroll
                    for (int d = 0; d < 8; ++d)
                        p = fmaf(xf[d], Sc[k * 8 + d], p);
                    code |= (p > 0.f) ? (1u << k) : 0u;
                    pmin = fminf(pmin, fabsf(p));
                }
                if (pmin < 1e-4f) {  // rare: redo channel in fp64
                    const double* Sd = S64 + c * 120;
                    const double* Td = T64 + c * 15;
                    code = 0;
#pragma unroll
                    for (int k = 0; k < K15_; ++k) {
                        double p = -Td[k];
#pragma unroll
                        for (int d = 0; d < 8; ++d)
                            p = fma((double)xf[d], Sd[k * 8 + d], p);
                        code |= (p > 0.0) ? (1u << k) : 0u;
                    }
                }
            } else {
                const double* Sc = S64 + c * 120;  // k-major: Sc[k*8+d]
                const double* Tc = T64 + c * 15;
                double xd[8];
#pragma unroll
                for (int d = 0; d < 8; ++d)
                    xd[d] = (double)xls[cl * XST2 + lane * 9 + d];
#pragma unroll
                for (int k = 0; k < K15_; ++k) {
                    double p = -Tc[k];
#pragma unroll
                    for (int d = 0; d < 8; ++d)
                        p = fma(xd[d], Sc[k * 8 + d], p);
                    code |= (p > 0.0) ? (1u << k) : 0u;
                }
            }
            codesh[lane * CPAD + r * 8 + cl] = (uint16_t)code;
        }
    }
    __syncthreads();

    // End phase: thread (bb,q) owns batch bb, local channels q*8..q*8+7.
    int bb = threadIdx.x >> 2;
    int q = threadIdx.x & 3;
    uint4 cw4 = *(const uint4*)&codesh[bb * CPAD + q * 8];  // one b128
    uint16_t cds[8];
    cds[0] = (uint16_t)(cw4.x & 0xFFFF); cds[1] = (uint16_t)(cw4.x >> 16);
    cds[2] = (uint16_t)(cw4.y & 0xFFFF); cds[3] = (uint16_t)(cw4.y >> 16);
    cds[4] = (uint16_t)(cw4.z & 0xFFFF); cds[5] = (uint16_t)(cw4.z >> 16);
    cds[6] = (uint16_t)(cw4.w & 0xFFFF); cds[7] = (uint16_t)(cw4.w >> 16);
    uint8_t ids[8];
#pragma unroll
    for (int j = 0; j < 8; ++j) ids[j] = amap[cds[j]];  // 8 indep gathers

    if (FAST) {
        int row = b0 + bb;
        int rg = row >> 10;
        int tr = row & 127;
        int i_ = (row & 1023) >> 7;
        uint8_t* base = pcT + rg * 1024 + tr * 8 + i_;
#pragma unroll
        for (int j = 0; j < 4; ++j) {
            int p = hb * 16 + q * 4 + j;
            base[p * 32768] = (uint8_t)((ids[2 * j] << 4) | ids[2 * j + 1]);
        }
    } else {
        uint32_t w0 = (uint32_t)ids[0] | ((uint32_t)ids[1] << 8) |
                      ((uint32_t)ids[2] << 16) | ((uint32_t)ids[3] << 24);
        uint32_t w1 = (uint32_t)ids[4] | ((uint32_t)ids[5] << 8) |
                      ((uint32_t)ids[6] << 16) | ((uint32_t)ids[7] << 24);
        uint32_t* o =
            (uint32_t*)(idxo + (size_t)(b0 + bb) * 64 + hb * 32 + q * 8);
        o[0] = w0; o[1] = w1;
    }
}

// ---------------------------------------------------------------------------
// k_main8: streaming-staged gather, v4 (unchanged this round).
// Slab staged via global_load_lds (width 16), linear [256][16] fp16 rows;
// double-buffered 2x8 KB -> 8 blocks/CU; prefetch issued right after the
// barrier; compiler's vmcnt(0)-before-s_barrier is the drain we need.
// jc->XCD pinning: blocks sharing jc are blk = jc+32k -> same XCD L2.
// ---------------------------------------------------------------------------
__global__ __launch_bounds__(256, 8) void k_main8(const uint8_t* __restrict__ pcT,
                                                  const _Float16* __restrict__ P5,
                                                  float* __restrict__ out) {
    __shared__ alignas(16) _Float16 slab[2][256 * 16];  // 8 KB per buffer, linear

    int rg5 = blockIdx.x >> 5;   // 0..63, owns rows rg5*512 + i*128 + tr
    int jc = blockIdx.x & 31;
    int t = threadIdx.x;
    int tc = t & 1;        // which 8-half piece of the 16-half chunk
    int tr = t >> 1;       // 0..127
    int lane = t & 63;
    int wv = __builtin_amdgcn_readfirstlane(t >> 6);  // wave-uniform

    // pcT[p][rg][tr][i_]: for row = rg5*512 + i*128 + tr:
    //   rg = rg5>>1, i_ = (rg5&1)*4 + i  -> 4 consecutive bytes
    const uint8_t* cbase = pcT + (rg5 >> 1) * 1024 + tr * 8 + (rg5 & 1) * 4;

    float acc[4][8];
#pragma unroll
    for (int i = 0; i < 4; ++i)
#pragma unroll
        for (int e = 0; e < 8; ++e) acc[i][e] = 0.f;

    // staging: wave wv covers halfs [wv*512 + lane*8) and [+2048) of the
    // 4096-half slab; global src mirrors the linear LDS dest exactly.
    int hoff = wv * 512 + lane * 8;

    // prologue: issue p=0 stage + load cw0
    {
        const _Float16* g = P5 + (size_t)jc * 4096 + hoff;
        gld_lds16(g, &slab[0][wv * 512]);
        gld_lds16(g + 2048, &slab[0][wv * 512 + 2048]);
    }
    uint32_t cw = *(const uint32_t*)cbase;
    uint32_t cwn = 0;

    for (int p = 0; p < 32; ++p) {
        // compiler emits s_waitcnt vmcnt(0) before s_barrier -> slab[p&1]
        // landed; barrier also fences gather(p-1) vs stage(p+1) (same buf).
        __syncthreads();

        if (p < 31) {
            const _Float16* g =
                P5 + (size_t)((p + 1) * 32 + jc) * 4096 + hoff;
            _Float16* d = &slab[(p + 1) & 1][wv * 512];
            gld_lds16(g, d);
            gld_lds16(g + 2048, d + 2048);
            cwn = *(const uint32_t*)(cbase + (size_t)(p + 1) * 32768);
        }

        const _Float16* rb = &slab[p & 1][0] + tc * 8;
        uint32_t cw_cur = cw;
#pragma unroll
        for (int i = 0; i < 4; ++i) {
            int ci = (int)((cw_cur >> (8 * i)) & 0xFF);
            half8 v = *(const half8*)(rb + ci * 16);  // one ds_read_b128
#pragma unroll
            for (int e = 0; e < 8; ++e)
                acc[i][e] = fmaf((float)v[e], 1.0f, acc[i][e]);
        }
        cw = cwn;
    }

#pragma unroll
    for (int i = 0; i < 4; ++i) {
        int row = rg5 * 512 + i * 128 + tr;
        float* o = out + (size_t)row * 512 + jc * 16 + tc * 8;
        float4 w0;
        w0.x = acc[i][0]; w0.y = acc[i][1]; w0.z = acc[i][2]; w0.w = acc[i][3];
        float4 w1;
        w1.x = acc[i][4]; w1.y = acc[i][5]; w1.z = acc[i][6]; w1.w = acc[i][7];
        ((float4*)o)[0] = w0;
        ((float4*)o)[1] = w1;
    }
}

// Fallback (small ws): direct 64-channel gather from fp32 LUT.
__global__ __launch_bounds__(256) void k_main_direct(const uint8_t* __restrict__ idx,
                                                     const float* __restrict__ LUT,
                                                     float* __restrict__ out) {
    int j4 = threadIdx.x & 127;
    int sub = threadIdx.x >> 7;
    int b0 = blockIdx.x * 16 + sub * 8;
    const float4* L4 = (const float4*)LUT;
    for (int r = 0; r < 8; ++r) {
        int b = b0 + r;
        const uint32_t* iw = (const uint32_t*)(idx + (size_t)b * 64);
        float4 acc;
        acc.x = 0.f; acc.y = 0.f; acc.z = 0.f; acc.w = 0.f;
#pragma unroll
        for (int i = 0; i < 16; ++i) {
            uint32_t w = __builtin_amdgcn_readfirstlane(iw[i]);
#pragma unroll
            for (int t = 0; t < 4; ++t) {
                int c = i * 4 + t;
                uint32_t codev = (w >> (8 * t)) & 0xFu;
                float4 v = L4[(size_t)(c * 16 + codev) * 128 + j4];
                acc.x += v.x; acc.y += v.y; acc.z += v.z; acc.w += v.w;
            }
        }
        ((float4*)(out + (size_t)b * 512))[j4] = acc;
    }
}

extern "C" void kernel_launch(void* const* d_in, const int* in_sizes, int n_in,
                              void* d_out, int out_size, void* d_ws, size_t ws_size,
                              hipStream_t stream) {
    const float* x   = (const float*)d_in[0];
    const float* S   = (const float*)d_in[1];
    const float* H   = (const float*)d_in[2];
    const float* T   = (const float*)d_in[3];
    const float* LUT = (const float*)d_in[4];
    float* out = (float*)d_out;

    uint8_t* ws = (uint8_t*)d_ws;
    uint8_t* amap = ws + AMAP_OFF;
    double* S64   = (double*)(ws + S64_OFF);
    double* T64   = (double*)(ws + T64_OFF);
    uint8_t* idxb = ws + IDX_OFF;                  // fallback mode only
    float* S32    = (float*)(ws + IDX_OFF);        // pairs mode only
    float* T32    = (float*)(ws + IDX_OFF + S32_SZ);
    uint8_t* pcTb = ws + PCT_OFF;
    _Float16* P5  = (_Float16*)(ws + PTAB_OFF);

    bool use_pairs = ws_size >= WS_NEED;

    hipLaunchKernelGGL(k_setup, dim3(use_pairs ? 2048 : 129), dim3(256), 0,
                       stream, LUT, H, S, T, P5, amap, S64, T64, S32, T32,
                       use_pairs ? 1 : 0);
    if (use_pairs) {
        hipLaunchKernelGGL((k_codes4<1>), dim3(B_ / 64 * 2), dim3(256), 0,
                           stream, x, S64, T64, S32, T32, amap, idxb, pcTb);
        hipLaunchKernelGGL(k_main8, dim3(2048), dim3(256), 0, stream,
                           pcTb, P5, out);
    } else {
        hipLaunchKernelGGL((k_codes4<0>), dim3(B_ / 64 * 2), dim3(256), 0,
                           stream, x, S64, T64, S32, T32, amap, idxb, pcTb);
        hipLaunchKernelGGL(k_main_direct, dim3(B_ / 16), dim3(256), 0, stream,
                           idxb, LUT, out);
    }
}

// Round 6
// 165.673 us; speedup vs baseline: 1.1458x; 1.0527x over previous
//
#include <hip/hip_runtime.h>
#include <stdint.h>

#define B_    32768
#define C_    64
#define D_    8
#define K15_  15
#define K16_  16
#define OUT_  512

typedef _Float16 half4v __attribute__((ext_vector_type(4)));
typedef _Float16 half8  __attribute__((ext_vector_type(8)));
typedef uint32_t uint4v __attribute__((ext_vector_type(4)));

// workspace layout (bytes)
#define AMAP_OFF  0
#define AMAP_SZ   32768                  // uint8 argmax per 15-bit code
#define S64_OFF   32768                  // fp64 S, k-major: S64[c][k][d]
#define S64_SZ    (64 * 15 * 8 * 8)      // 61440
#define T64_OFF   (S64_OFF + S64_SZ)     // 94208
#define T64_SZ    (64 * 15 * 8)          // 7680
#define IDX_OFF   (T64_OFF + T64_SZ)     // 101888
#define IDX_SZ    (B_ * C_)              // 2 MB. pairs mode: idxo unused ->
                                         // region reused for S32/T32 (fp32,
                                         // k-major) so WS_NEED is unchanged.
#define S32_SZ    (64 * 15 * 8 * 4)      // 30720
#define PCT_OFF   (IDX_OFF + IDX_SZ)     // 2199040
#define PCT_SZ    (B_ * 32)              // 1 MB: pcT[p][rg][tr][i]
#define PTAB_OFF  (PCT_OFF + PCT_SZ)     // 3247616 (16B aligned)
#define PTAB_SZ   (32 * 32 * 256 * 16 * 2) // 8388608: P5[p][jc][q][16] fp16
#define WS_NEED   ((size_t)PTAB_OFF + PTAB_SZ)

// global_load_lds, width 16 B: LDS dest is wave-uniform base + lane*16
// (m104/m173) -> LDS layout must be linear in lane order.
__device__ __forceinline__ void gld_lds16(const void* g, void* l) {
    __builtin_amdgcn_global_load_lds(
        (const __attribute__((address_space(1))) void*)g,
        (__attribute__((address_space(3))) void*)l, 16, 0, 0);
}

// acc += (float)f16  via v_fma_mix_f32 (exact: cvt exact, *1.0 exact, fp32
// add) -- guarantees 1 VALU op/elem instead of a possible cvt+add pair.
__device__ __forceinline__ void fma_mix_lo(float& acc, uint32_t w, float one) {
    asm("v_fma_mix_f32 %0, %1, %2, %0 op_sel_hi:[1,0,0]"
        : "+v"(acc) : "v"(w), "v"(one));
}
__device__ __forceinline__ void fma_mix_hi(float& acc, uint32_t w, float one) {
    asm("v_fma_mix_f32 %0, %1, %2, %0 op_sel:[1,0,0] op_sel_hi:[1,0,0]"
        : "+v"(acc) : "v"(w), "v"(one));
}

// ---------------------------------------------------------------------------
// k_setup (fused): 2048 blocks write P5 (j-first layout, fully coalesced
// 16B stores); blocks 0..127 also compute amap; block 128 builds S64/T64
// (+ S32/T32 fp32 copies when do_pairs).
// P5 half-index: ((p*32 + jc)*256 + q)*16 + e   (q = (t0<<4)|t1)
// ---------------------------------------------------------------------------
__global__ __launch_bounds__(256) void k_setup(const float* __restrict__ LUT,
                                               const float* __restrict__ H,
                                               const float* __restrict__ S,
                                               const float* __restrict__ T,
                                               _Float16* __restrict__ P5,
                                               uint8_t* __restrict__ amap,
                                               double* __restrict__ S64,
                                               double* __restrict__ T64,
                                               float* __restrict__ S32,
                                               float* __restrict__ T32,
                                               int do_pairs) {
    int gid = blockIdx.x * 256 + threadIdx.x;

    if (do_pairs) {
        // gid bits: [p:5][jc:5][q:8][e8:1] -> write offset = gid*8 halfs
        int e8 = gid & 1;
        int q = (gid >> 1) & 255;
        int jc = (gid >> 9) & 31;
        int p = gid >> 14;
        int t0 = q >> 4;
        int t1 = q & 15;
        int j0 = jc * 16 + e8 * 8;
        const float* u = LUT + (size_t)((2 * p) * 16 + t0) * 512 + j0;
        const float* v = LUT + (size_t)((2 * p + 1) * 16 + t1) * 512 + j0;
        float4 u0 = ((const float4*)u)[0];
        float4 u1 = ((const float4*)u)[1];
        float4 v0 = ((const float4*)v)[0];
        float4 v1 = ((const float4*)v)[1];
        half8 w;
        w[0] = (_Float16)(u0.x + v0.x);
        w[1] = (_Float16)(u0.y + v0.y);
        w[2] = (_Float16)(u0.z + v0.z);
        w[3] = (_Float16)(u0.w + v0.w);
        w[4] = (_Float16)(u1.x + v1.x);
        w[5] = (_Float16)(u1.y + v1.y);
        w[6] = (_Float16)(u1.z + v1.z);
        w[7] = (_Float16)(u1.w + v1.w);
        *(half8*)(P5 + (size_t)gid * 8) = w;
    }

    if (blockIdx.x < 128) {
        int code = gid;
        double h[K16_];
#pragma unroll
        for (int j = 0; j < K16_; ++j) h[j] = 0.0;
#pragma unroll
        for (int k = 0; k < K15_; ++k) {
            double s = ((code >> k) & 1) ? 1.0 : -1.0;
#pragma unroll
            for (int j = 0; j < K16_; ++j) h[j] += s * (double)H[k * K16_ + j];
        }
        double best = h[0];
        int bi = 0;
#pragma unroll
        for (int j = 1; j < K16_; ++j) {
            if (h[j] > best) { best = h[j]; bi = j; }
        }
        amap[code] = (uint8_t)bi;
    } else if (blockIdx.x == 128) {
        for (int i = threadIdx.x; i < 64 * 15 * 8; i += 256) {
            int c = i / 120;
            int r = i - c * 120;  // r = k*8 + d
            int k = r >> 3;
            int d = r & 7;
            float sv = S[c * 120 + d * 15 + k];
            S64[i] = (double)sv;
            if (do_pairs) S32[i] = sv;
        }
        for (int i = threadIdx.x; i < 64 * 15; i += 256) {
            T64[i] = (double)T[i];
            if (do_pairs) T32[i] = T[i];
        }
    }
}

// ---------------------------------------------------------------------------
// k_codes5: block = (batch-group of 64) x (channel-quarter of 16). Grid 2048.
// v4 ran at 30% HBM: stage->barrier->compute left zero loads in flight during
// compute (latency duty-cycle bound). v5 = T14 async-stage:
//   * 2 rounds of 8 channels; round r+1's x (4 float4/thread) issued right
//     AFTER the barrier preceding round r's compute -> loads fly under the
//     ~500cy FMA chain; the vmcnt(0) the compiler puts before the NEXT
//     barrier is exactly where the data is needed (ds_write after it).
//   * grid 2048 (4x blocks) + LDS 21.6 KB -> 6 blocks/CU: unaligned stalls.
// Numerics unchanged: fp32 dots + fp64 rescue when min|p| < 1e-4 (codes
// bit-identical to all-fp64).
// ---------------------------------------------------------------------------
#define XST3 579   // odd -> compute reads 2-way (free); stage banks spread
#define CPAD2 24   // uint16 row pad: 48 B rows -> 8B-aligned b64 end reads
template <int FAST>
__global__ __launch_bounds__(256, 6) void k_codes5(const float* __restrict__ x,
                                                   const double* __restrict__ S64,
                                                   const double* __restrict__ T64,
                                                   const float* __restrict__ S32,
                                                   const float* __restrict__ T32,
                                                   const uint8_t* __restrict__ amap,
                                                   uint8_t* __restrict__ idxo,
                                                   uint8_t* __restrict__ pcT) {
    __shared__ float xls[8 * XST3];                     // 8 ch x 64 b x 9
    __shared__ alignas(16) uint16_t codesh[64 * CPAD2]; // [batch][local ch]

    int bg = blockIdx.x >> 2;        // batch group: rows bg*64 .. +63
    int cq = blockIdx.x & 3;         // channel quarter: channels cq*16 .. +15
    int b0 = bg * 64;
    int lane = threadIdx.x & 63;
    int wv = __builtin_amdgcn_readfirstlane(threadIdx.x >> 6);
    int tid = threadIdx.x;

    // --- stage helpers (round r covers global channels cq*16 + r*8 + [0,8)
    //     = x columns cq*128 + r*64 + [0,64)) ---
    float4 rgA[4], rgB[4];
#pragma unroll
    for (int t2 = 0; t2 < 4; ++t2) {   // prologue: load round 0
        int e = t2 * 256 + tid;
        int b = e >> 4;
        int j4 = e & 15;
        rgA[t2] = *(const float4*)(x + (size_t)(b0 + b) * 512 + cq * 128 +
                                   0 * 64 + j4 * 4);
    }
#pragma unroll
    for (int t2 = 0; t2 < 4; ++t2) {   // write round 0 to LDS
        int e = t2 * 256 + tid;
        int b = e >> 4;
        int j4 = e & 15;
        int cl = j4 >> 1;
        int d0 = (j4 & 1) * 4;
        float* dst = &xls[cl * XST3 + b * 9 + d0];
        dst[0] = rgA[t2].x; dst[1] = rgA[t2].y;
        dst[2] = rgA[t2].z; dst[3] = rgA[t2].w;
    }
    __syncthreads();   // bar1: xls(round0) visible

#pragma unroll
    for (int t2 = 0; t2 < 4; ++t2) {   // issue round 1 loads NOW (fly under compute)
        int e = t2 * 256 + tid;
        int b = e >> 4;
        int j4 = e & 15;
        rgB[t2] = *(const float4*)(x + (size_t)(b0 + b) * 512 + cq * 128 +
                                   1 * 64 + j4 * 4);
    }

#pragma unroll
    for (int r = 0; r < 2; ++r) {
#pragma unroll
        for (int i = 0; i < 2; ++i) {
            int cl = wv + i * 4;                 // wave-uniform, 0..7
            int c = cq * 16 + r * 8 + cl;        // global channel
            unsigned code = 0;
            if (FAST) {
                const float* Sc = S32 + c * 120;  // k-major: Sc[k*8+d]
                const float* Tc = T32 + c * 15;
                float xf[8];
#pragma unroll
                for (int d = 0; d < 8; ++d)
                    xf[d] = xls[cl * XST3 + lane * 9 + d];
                float pmin = 3.0e38f;
#pragma unroll
                for (int k = 0; k < K15_; ++k) {
                    float p = -Tc[k];
#pragma unroll
                    for (int d = 0; d < 8; ++d)
                        p = fmaf(xf[d], Sc[k * 8 + d], p);
                    code |= (p > 0.f) ? (1u << k) : 0u;
                    pmin = fminf(pmin, fabsf(p));
                }
                if (pmin < 1e-4f) {  // rare: redo channel in fp64
                    const double* Sd = S64 + c * 120;
                    const double* Td = T64 + c * 15;
                    code = 0;
#pragma unroll
                    for (int k = 0; k < K15_; ++k) {
                        double p = -Td[k];
#pragma unroll
                        for (int d = 0; d < 8; ++d)
                            p = fma((double)xf[d], Sd[k * 8 + d], p);
                        code |= (p > 0.0) ? (1u << k) : 0u;
                    }
                }
            } else {
                const double* Sc = S64 + c * 120;
                const double* Tc = T64 + c * 15;
                double xd[8];
#pragma unroll
                for (int d = 0; d < 8; ++d)
                    xd[d] = (double)xls[cl * XST3 + lane * 9 + d];
#pragma unroll
                for (int k = 0; k < K15_; ++k) {
                    double p = -Tc[k];
#pragma unroll
                    for (int d = 0; d < 8; ++d)
                        p = fma(xd[d], Sc[k * 8 + d], p);
                    code |= (p > 0.0) ? (1u << k) : 0u;
                }
            }
            codesh[lane * CPAD2 + r * 8 + cl] = (uint16_t)code;
        }
        if (r == 0) {
            __syncthreads();   // bar2: xls(round0) reads done; rgB landed
#pragma unroll
            for (int t2 = 0; t2 < 4; ++t2) {   // write round 1 to LDS
                int e = t2 * 256 + tid;
                int b = e >> 4;
                int j4 = e & 15;
                int cl = j4 >> 1;
                int d0 = (j4 & 1) * 4;
                float* dst = &xls[cl * XST3 + b * 9 + d0];
                dst[0] = rgB[t2].x; dst[1] = rgB[t2].y;
                dst[2] = rgB[t2].z; dst[3] = rgB[t2].w;
            }
            __syncthreads();   // bar3: xls(round1) visible
        }
    }
    __syncthreads();   // bar4: codesh complete

    // End phase: thread (bb,sub) owns batch bb, channels cq*16+sub*4..+3.
    int bb = tid >> 2;
    int sub = tid & 3;
    uint64_t cw8 = *(const uint64_t*)&codesh[bb * CPAD2 + sub * 4];  // one b64
    uint16_t cds[4];
    cds[0] = (uint16_t)(cw8 & 0xFFFF);
    cds[1] = (uint16_t)((cw8 >> 16) & 0xFFFF);
    cds[2] = (uint16_t)((cw8 >> 32) & 0xFFFF);
    cds[3] = (uint16_t)(cw8 >> 48);
    uint8_t ids[4];
#pragma unroll
    for (int j = 0; j < 4; ++j) ids[j] = amap[cds[j]];  // 4 indep gathers

    if (FAST) {
        int row = b0 + bb;
        int rg = row >> 10;
        int tr = row & 127;
        int i_ = (row & 1023) >> 7;
        uint8_t* base = pcT + rg * 1024 + tr * 8 + i_;
        int p0 = cq * 8 + sub * 2;
        base[(size_t)p0 * 32768] = (uint8_t)((ids[0] << 4) | ids[1]);
        base[(size_t)(p0 + 1) * 32768] = (uint8_t)((ids[2] << 4) | ids[3]);
    } else {
        uint32_t w0 = (uint32_t)ids[0] | ((uint32_t)ids[1] << 8) |
                      ((uint32_t)ids[2] << 16) | ((uint32_t)ids[3] << 24);
        *(uint32_t*)(idxo + (size_t)(b0 + bb) * 64 + cq * 16 + sub * 4) = w0;
    }
}

// ---------------------------------------------------------------------------
// k_main9: streaming-staged gather, v5.
// Change vs k_main8: accumulation via inline-asm v_fma_mix_f32 (1 VALU
// op/elem guaranteed; numerically identical to fmaf((float)h,1,acc)).
// LDS pipe (~83% busy: 49K read + 29K conflict + 16K staging cy/CU) is the
// structural floor; this removes the VALU excess that was pacing it.
// Everything else identical to k_main8 (conflict fingerprint 7521216).
// ---------------------------------------------------------------------------
__global__ __launch_bounds__(256, 8) void k_main9(const uint8_t* __restrict__ pcT,
                                                  const _Float16* __restrict__ P5,
                                                  float* __restrict__ out) {
    __shared__ alignas(16) _Float16 slab[2][256 * 16];  // 8 KB per buffer, linear

    int rg5 = blockIdx.x >> 5;   // 0..63, owns rows rg5*512 + i*128 + tr
    int jc = blockIdx.x & 31;
    int t = threadIdx.x;
    int tc = t & 1;        // which 8-half piece of the 16-half chunk
    int tr = t >> 1;       // 0..127
    int lane = t & 63;
    int wv = __builtin_amdgcn_readfirstlane(t >> 6);  // wave-uniform

    // pcT[p][rg][tr][i_]: for row = rg5*512 + i*128 + tr:
    //   rg = rg5>>1, i_ = (rg5&1)*4 + i  -> 4 consecutive bytes
    const uint8_t* cbase = pcT + (rg5 >> 1) * 1024 + tr * 8 + (rg5 & 1) * 4;

    float acc[4][8];
#pragma unroll
    for (int i = 0; i < 4; ++i)
#pragma unroll
        for (int e = 0; e < 8; ++e) acc[i][e] = 0.f;
    float one = 1.0f;

    // staging: wave wv covers halfs [wv*512 + lane*8) and [+2048) of the
    // 4096-half slab; global src mirrors the linear LDS dest exactly.
    int hoff = wv * 512 + lane * 8;

    // prologue: issue p=0 stage + load cw0
    {
        const _Float16* g = P5 + (size_t)jc * 4096 + hoff;
        gld_lds16(g, &slab[0][wv * 512]);
        gld_lds16(g + 2048, &slab[0][wv * 512 + 2048]);
    }
    uint32_t cw = *(const uint32_t*)cbase;
    uint32_t cwn = 0;

    for (int p = 0; p < 32; ++p) {
        // compiler emits s_waitcnt vmcnt(0) before s_barrier -> slab[p&1]
        // landed; barrier also fences gather(p-1) vs stage(p+1) (same buf).
        __syncthreads();

        if (p < 31) {
            const _Float16* g =
                P5 + (size_t)((p + 1) * 32 + jc) * 4096 + hoff;
            _Float16* d = &slab[(p + 1) & 1][wv * 512];
            gld_lds16(g, d);
            gld_lds16(g + 2048, d + 2048);
            cwn = *(const uint32_t*)(cbase + (size_t)(p + 1) * 32768);
        }

        const _Float16* rb = &slab[p & 1][0] + tc * 8;
        uint32_t cw_cur = cw;
#pragma unroll
        for (int i = 0; i < 4; ++i) {
            int ci = (int)((cw_cur >> (8 * i)) & 0xFF);
            half8 v = *(const half8*)(rb + ci * 16);  // one ds_read_b128
            uint4v w = __builtin_bit_cast(uint4v, v);
#pragma unroll
            for (int e2 = 0; e2 < 4; ++e2) {
                fma_mix_lo(acc[i][2 * e2], w[e2], one);
                fma_mix_hi(acc[i][2 * e2 + 1], w[e2], one);
            }
        }
        cw = cwn;
    }

#pragma unroll
    for (int i = 0; i < 4; ++i) {
        int row = rg5 * 512 + i * 128 + tr;
        float* o = out + (size_t)row * 512 + jc * 16 + tc * 8;
        float4 w0;
        w0.x = acc[i][0]; w0.y = acc[i][1]; w0.z = acc[i][2]; w0.w = acc[i][3];
        float4 w1;
        w1.x = acc[i][4]; w1.y = acc[i][5]; w1.z = acc[i][6]; w1.w = acc[i][7];
        ((float4*)o)[0] = w0;
        ((float4*)o)[1] = w1;
    }
}

// Fallback (small ws): direct 64-channel gather from fp32 LUT.
__global__ __launch_bounds__(256) void k_main_direct(const uint8_t* __restrict__ idx,
                                                     const float* __restrict__ LUT,
                                                     float* __restrict__ out) {
    int j4 = threadIdx.x & 127;
    int sub = threadIdx.x >> 7;
    int b0 = blockIdx.x * 16 + sub * 8;
    const float4* L4 = (const float4*)LUT;
    for (int r = 0; r < 8; ++r) {
        int b = b0 + r;
        const uint32_t* iw = (const uint32_t*)(idx + (size_t)b * 64);
        float4 acc;
        acc.x = 0.f; acc.y = 0.f; acc.z = 0.f; acc.w = 0.f;
#pragma unroll
        for (int i = 0; i < 16; ++i) {
            uint32_t w = __builtin_amdgcn_readfirstlane(iw[i]);
#pragma unroll
            for (int t = 0; t < 4; ++t) {
                int c = i * 4 + t;
                uint32_t codev = (w >> (8 * t)) & 0xFu;
                float4 v = L4[(size_t)(c * 16 + codev) * 128 + j4];
                acc.x += v.x; acc.y += v.y; acc.z += v.z; acc.w += v.w;
            }
        }
        ((float4*)(out + (size_t)b * 512))[j4] = acc;
    }
}

extern "C" void kernel_launch(void* const* d_in, const int* in_sizes, int n_in,
                              void* d_out, int out_size, void* d_ws, size_t ws_size,
                              hipStream_t stream) {
    const float* x   = (const float*)d_in[0];
    const float* S   = (const float*)d_in[1];
    const float* H   = (const float*)d_in[2];
    const float* T   = (const float*)d_in[3];
    const float* LUT = (const float*)d_in[4];
    float* out = (float*)d_out;

    uint8_t* ws = (uint8_t*)d_ws;
    uint8_t* amap = ws + AMAP_OFF;
    double* S64   = (double*)(ws + S64_OFF);
    double* T64   = (double*)(ws + T64_OFF);
    uint8_t* idxb = ws + IDX_OFF;                  // fallback mode only
    float* S32    = (float*)(ws + IDX_OFF);        // pairs mode only
    float* T32    = (float*)(ws + IDX_OFF + S32_SZ);
    uint8_t* pcTb = ws + PCT_OFF;
    _Float16* P5  = (_Float16*)(ws + PTAB_OFF);

    bool use_pairs = ws_size >= WS_NEED;

    hipLaunchKernelGGL(k_setup, dim3(use_pairs ? 2048 : 129), dim3(256), 0,
                       stream, LUT, H, S, T, P5, amap, S64, T64, S32, T32,
                       use_pairs ? 1 : 0);
    if (use_pairs) {
        hipLaunchKernelGGL((k_codes5<1>), dim3(B_ / 64 * 4), dim3(256), 0,
                           stream, x, S64, T64, S32, T32, amap, idxb, pcTb);
        hipLaunchKernelGGL(k_main9, dim3(2048), dim3(256), 0, stream,
                           pcTb, P5, out);
    } else {
        hipLaunchKernelGGL((k_codes5<0>), dim3(B_ / 64 * 4), dim3(256), 0,
                           stream, x, S64, T64, S32, T32, amap, idxb, pcTb);
        hipLaunchKernelGGL(k_main_direct, dim3(B_ / 16), dim3(256), 0, stream,
                           idxb, LUT, out);
    }
}